// Round 14
// baseline (461.685 us; speedup 1.0000x reference)
//
#include <hip/hip_runtime.h>

#define NG 4
#define NN 50000
#define NE 800000
#define NC 128
#define NB 196              // ceil(NN/256) buckets of 256 nodes per graph
#define NBT (NG * NB)       // 784 total buckets
#define CAPB 48             // LDS bin capacity in scatter (lambda~21, +6 sigma)
#define LBS (NB + 1)        // lbin stride 197 (odd -> conflict-free flush)
#define CAPQ 4608           // fixed bucket capacity (lambda 4096, +8 sigma)
#define GEMM_BLKS 784       // 196 row-tiles (256 rows) x 4 graphs

typedef _Float16 half8 __attribute__((ext_vector_type(8)));
typedef _Float16 half4 __attribute__((ext_vector_type(4)));
typedef float f32x4 __attribute__((ext_vector_type(4)));

// ---------------------------------------------------------------- utilities
__global__ __launch_bounds__(256) void init_cursors(int* __restrict__ bktCur) {
  int i = blockIdx.x * blockDim.x + threadIdx.x;
  if (i < NBT) bktCur[i] = i * CAPQ;
}

// ---------------- FAT kernel: [gemm L1 (unscaled h'')]  ||  [bucket_scatter]
// hbuf layout: SLOT layout — slot p of a row holds true col ((p&7)<<4)|(p>>3).
__global__ __launch_bounds__(512) void fat_gemm1_scatter(
    const float* __restrict__ x, const float* __restrict__ W,
    _Float16* __restrict__ h, const int* __restrict__ ei,
    int* __restrict__ bktCur, unsigned int* __restrict__ rec) {
  __shared__ char smem[65536];
  int bid = blockIdx.x;
  int tid = threadIdx.x;
  if (bid < GEMM_BLKS) {
    _Float16* Wt0 = (_Float16*)smem;
    _Float16* Wt1 = Wt0 + 128 * 128;
    int g = bid / 196;
    int row0 = (bid % 196) * 256;
    int lane = tid & 63;
    int wv = tid >> 6;          // 0..7
    int kc = lane >> 4;
    int lr = lane & 15;
    const float* Wg = W + (size_t)g * NC * NC;
    const float* xg = x + (size_t)g * NN * NC;
    {
      int n = tid & 127;
      int kq = (tid >> 7) & 3;
      #pragma unroll
      for (int it = 0; it < 8; ++it) {
        int k4 = it * 16 + kq * 4;
        float w0 = Wg[(size_t)(k4 + 0) * NC + n];
        float w1 = Wg[(size_t)(k4 + 1) * NC + n];
        float w2 = Wg[(size_t)(k4 + 2) * NC + n];
        float w3 = Wg[(size_t)(k4 + 3) * NC + n];
        half4 hi, lo;
        hi[0] = (_Float16)w0; lo[0] = (_Float16)(w0 - (float)hi[0]);
        hi[1] = (_Float16)w1; lo[1] = (_Float16)(w1 - (float)hi[1]);
        hi[2] = (_Float16)w2; lo[2] = (_Float16)(w2 - (float)hi[2]);
        hi[3] = (_Float16)w3; lo[3] = (_Float16)(w3 - (float)hi[3]);
        int chunk = k4 >> 3;
        int base = n * 128 + ((chunk ^ (n & 15)) << 3) + (k4 & 4);
        *(half4*)&Wt0[base] = hi;
        *(half4*)&Wt1[base] = lo;
      }
    }
    __syncthreads();
    f32x4 acc[2][8];
    #pragma unroll
    for (int mb = 0; mb < 2; ++mb)
      #pragma unroll
      for (int nb = 0; nb < 8; ++nb)
        acc[mb][nb] = (f32x4){0.f, 0.f, 0.f, 0.f};
    for (int kstep = 0; kstep < 4; ++kstep) {
      half8 ah[2], al[2];
      #pragma unroll
      for (int mb = 0; mb < 2; ++mb) {
        int row = row0 + wv * 32 + mb * 16 + lr;
        if (row > NN - 1) row = NN - 1;
        const float* xp = xg + (size_t)row * NC + kstep * 32 + kc * 8;
        float4 v0 = *(const float4*)xp;
        float4 v1 = *(const float4*)(xp + 4);
        float vv[8] = {v0.x, v0.y, v0.z, v0.w, v1.x, v1.y, v1.z, v1.w};
        #pragma unroll
        for (int i = 0; i < 8; ++i) {
          _Float16 t = (_Float16)vv[i];
          ah[mb][i] = t; al[mb][i] = (_Float16)(vv[i] - (float)t);
        }
      }
      #pragma unroll
      for (int nb = 0; nb < 8; ++nb) {
        int n = nb * 16 + lr;
        int chunk = kstep * 4 + kc;
        int boff = n * 128 + ((chunk ^ (n & 15)) << 3);
        half8 bh = *(const half8*)&Wt0[boff];
        half8 bl = *(const half8*)&Wt1[boff];
        #pragma unroll
        for (int mb = 0; mb < 2; ++mb) {
          acc[mb][nb] = __builtin_amdgcn_mfma_f32_16x16x32_f16(ah[mb], bh, acc[mb][nb], 0, 0, 0);
          acc[mb][nb] = __builtin_amdgcn_mfma_f32_16x16x32_f16(al[mb], bh, acc[mb][nb], 0, 0, 0);
          acc[mb][nb] = __builtin_amdgcn_mfma_f32_16x16x32_f16(ah[mb], bl, acc[mb][nb], 0, 0, 0);
        }
      }
    }
    _Float16* hg = h + (size_t)g * NN * NC;
    #pragma unroll
    for (int mb = 0; mb < 2; ++mb) {
      #pragma unroll
      for (int reg = 0; reg < 4; ++reg) {
        int row = row0 + wv * 32 + mb * 16 + kc * 4 + reg;
        if (row < NN) {
          half8 o;
          #pragma unroll
          for (int nb = 0; nb < 8; ++nb)
            o[nb] = (_Float16)acc[mb][nb][reg];     // UNSCALED h'', slot layout
          *(half8*)(hg + (size_t)row * NC + lr * 8) = o;
        }
      }
    }
  } else {
    int* lcnt = (int*)smem;
    int* lbase = lcnt + NB;
    unsigned int* lbin = (unsigned int*)(smem + 2048);   // 37824B, fits
    int sb = bid - GEMM_BLKS;
    int g = sb / 196;
    int e0 = (sb % 196) * 4096;
    for (int i = tid; i < NB; i += 512) lcnt[i] = 0;
    __syncthreads();
    const int* srcp = ei + (size_t)g * 2 * NE;
    const int* dstp = srcp + NE;
    for (int t = tid; t < 4096; t += 512) {
      int e = e0 + t;
      if (e < NE) {
        int s = srcp[e], d = dstp[e];
        int b = d >> 8;
        unsigned int r = ((unsigned int)(d & 255) << 16) | (unsigned int)s;
        int pos = atomicAdd(&lcnt[b], 1);
        if (pos < CAPB) lbin[pos * LBS + b] = r;
        else { int gp = atomicAdd(&bktCur[g * NB + b], 1); rec[gp] = r; }  // rare
      }
    }
    __syncthreads();
    if (tid < NB) {
      int n = lcnt[tid]; if (n > CAPB) n = CAPB;
      lbase[tid] = n ? atomicAdd(&bktCur[g * NB + tid], n) : 0;
    }
    __syncthreads();
    int lane = tid & 63, wv = tid >> 6;
    for (int b = wv; b < NB; b += 8) {
      int n = lcnt[b]; if (n > CAPB) n = CAPB;
      if (lane < n) rec[lbase[b] + lane] = lbin[lane * LBS + b];
    }
  }
}

// Per (graph,bucket): LDS count -> scan -> rank into padded col[]. off/deg/dis.
__global__ __launch_bounds__(256) void build_csr(
    const unsigned int* __restrict__ rec, const int* __restrict__ bktCur,
    unsigned short* __restrict__ col, int* __restrict__ off,
    unsigned short* __restrict__ deg, float* __restrict__ dis) {
  __shared__ int cnt[256];
  __shared__ int offv[256];
  __shared__ int cnt2[256];
  __shared__ int wsum[4];
  int g = blockIdx.y, b = blockIdx.x;
  int idx = g * NB + b;
  int rb = idx * CAPQ, re = bktCur[idx];
  int tid = threadIdx.x;
  cnt[tid] = 0;
  __syncthreads();
  for (int j = rb + tid; j < re; j += 256)
    atomicAdd(&cnt[(rec[j] >> 16) & 255], 1);
  __syncthreads();
  int lane = tid & 63, wv = tid >> 6;
  int v = cnt[tid], incl = v;
  #pragma unroll
  for (int d2 = 1; d2 < 64; d2 <<= 1) {
    int t = __shfl_up(incl, d2, 64);
    if (lane >= d2) incl += t;
  }
  if (lane == 63) wsum[wv] = incl;
  __syncthreads();
  if (tid == 0) {
    int s = 0;
    #pragma unroll
    for (int w = 0; w < 4; ++w) { int t = wsum[w]; wsum[w] = s; s += t; }
  }
  __syncthreads();
  int excl = wsum[wv] + incl - v;
  offv[tid] = excl;
  cnt2[tid] = 0;
  int node = b * 256 + tid;
  if (node < NN) {
    off[g * (NN + 1) + node] = rb + excl;
    deg[(size_t)g * NN + node] = (unsigned short)v;
    dis[(size_t)g * NN + node] = rsqrtf((float)(v + 1));  // +1 self loop
  }
  __syncthreads();
  for (int j = rb + tid; j < re; j += 256) {
    unsigned int r = rec[j];
    int dl = (r >> 16) & 255;
    int p = rb + offv[dl] + atomicAdd(&cnt2[dl], 1);
    col[p] = (unsigned short)(r & 0xFFFF);
  }
}

// -------------------- fp16-input GEMM (layers 2,3): 512 thr, 256-row tile.
// INPUT xh is in SLOT layout; Wt staged with the same k-permutation
// (LDS slot s holds W[((s&7)<<4)|(s>>3)][n]) so A/B match slot-for-slot.
// Output hbuf in slot layout (epilogue unchanged).
__global__ __launch_bounds__(512) void gemm16_mfma_kernel(
    const _Float16* __restrict__ x, const float* __restrict__ W,
    const float* __restrict__ dis, _Float16* __restrict__ h) {
  __shared__ _Float16 Wt[2][128 * 128];
  int g = blockIdx.y;
  int row0 = blockIdx.x * 256;
  int tid = threadIdx.x;
  int lane = tid & 63;
  int wv = tid >> 6;            // 0..7
  int kc = lane >> 4;
  int lr = lane & 15;
  const float* Wg = W + (size_t)g * NC * NC;
  const _Float16* xg = x + (size_t)g * NN * NC;
  {
    int n = tid & 127;
    int kq = (tid >> 7) & 3;
    #pragma unroll
    for (int it = 0; it < 8; ++it) {
      int k4 = it * 16 + kq * 4;    // slot base (4 consecutive slots)
      int t0 = (((k4 + 0) & 7) << 4) | ((k4 + 0) >> 3);   // true k rows
      int t1 = (((k4 + 1) & 7) << 4) | ((k4 + 1) >> 3);
      int t2 = (((k4 + 2) & 7) << 4) | ((k4 + 2) >> 3);
      int t3 = (((k4 + 3) & 7) << 4) | ((k4 + 3) >> 3);
      float w0 = Wg[(size_t)t0 * NC + n];
      float w1 = Wg[(size_t)t1 * NC + n];
      float w2 = Wg[(size_t)t2 * NC + n];
      float w3 = Wg[(size_t)t3 * NC + n];
      half4 hi, lo;
      hi[0] = (_Float16)w0; lo[0] = (_Float16)(w0 - (float)hi[0]);
      hi[1] = (_Float16)w1; lo[1] = (_Float16)(w1 - (float)hi[1]);
      hi[2] = (_Float16)w2; lo[2] = (_Float16)(w2 - (float)hi[2]);
      hi[3] = (_Float16)w3; lo[3] = (_Float16)(w3 - (float)hi[3]);
      int chunk = k4 >> 3;
      int base = n * 128 + ((chunk ^ (n & 15)) << 3) + (k4 & 4);
      *(half4*)&Wt[0][base] = hi;
      *(half4*)&Wt[1][base] = lo;
    }
  }
  __syncthreads();
  f32x4 acc[2][8];
  #pragma unroll
  for (int mb = 0; mb < 2; ++mb)
    #pragma unroll
    for (int nb = 0; nb < 8; ++nb)
      acc[mb][nb] = (f32x4){0.f, 0.f, 0.f, 0.f};
  for (int kstep = 0; kstep < 4; ++kstep) {
    half8 ah[2];
    #pragma unroll
    for (int mb = 0; mb < 2; ++mb) {
      int row = row0 + wv * 32 + mb * 16 + lr;
      if (row > NN - 1) row = NN - 1;
      ah[mb] = *(const half8*)(xg + (size_t)row * NC + kstep * 32 + kc * 8);
    }
    #pragma unroll
    for (int nb = 0; nb < 8; ++nb) {
      int n = nb * 16 + lr;
      int chunk = kstep * 4 + kc;
      int boff = n * 128 + ((chunk ^ (n & 15)) << 3);
      half8 bh = *(const half8*)&Wt[0][boff];
      half8 bl = *(const half8*)&Wt[1][boff];
      #pragma unroll
      for (int mb = 0; mb < 2; ++mb) {
        acc[mb][nb] = __builtin_amdgcn_mfma_f32_16x16x32_f16(ah[mb], bh, acc[mb][nb], 0, 0, 0);
        acc[mb][nb] = __builtin_amdgcn_mfma_f32_16x16x32_f16(ah[mb], bl, acc[mb][nb], 0, 0, 0);
      }
    }
  }
  const float* disg = dis + (size_t)g * NN;
  _Float16* hg = h + (size_t)g * NN * NC;
  #pragma unroll
  for (int mb = 0; mb < 2; ++mb) {
    #pragma unroll
    for (int reg = 0; reg < 4; ++reg) {
      int row = row0 + wv * 32 + mb * 16 + kc * 4 + reg;
      if (row < NN) {
        float dsc = disg[row];
        half8 o;
        #pragma unroll
        for (int nb = 0; nb < 8; ++nb)
          o[nb] = (_Float16)(acc[mb][nb][reg] * dsc);
        *(half8*)(hg + (size_t)row * NC + lr * 8) = o;
      }
    }
  }
}

// ------------------- L1/L2 aggregation, SLOT-HALF split (fp16 slot-layout out)
// xcd = bid&7 -> graph = xcd>>1, slot-half hh = xcd&1.
// Gathers half4 at slot offset hh*64 + l*4 (128B/node-half = one L2 line);
// per-XCD working set 6.4MB. Bias uses true-col map c=((p&7)<<4)|(p>>3).
#define MIXACC(A, H) A = fmaf((float)(H), 1.0f, A)
#define MIXS(A, H, S) A = fmaf((float)(H), S, A)
template <bool GDIS>
__global__ __launch_bounds__(256) void agg_slot_kernel(
    const _Float16* __restrict__ h, const int* __restrict__ off,
    const unsigned short* __restrict__ col, const unsigned short* __restrict__ deg,
    const float* __restrict__ dis, const float* __restrict__ b,
    _Float16* __restrict__ outh) {
  int bid = blockIdx.x;
  int xcd = bid & 7;
  int g = xcd >> 1;
  int hh = xcd & 1;
  int sub = bid >> 3;
  int node = sub * 16 + (threadIdx.x >> 4);
  if (node >= NN) return;
  int l = threadIdx.x & 15;
  int so = hh * 64 + l * 4;               // slot offset of this lane's 4 slots
  const _Float16* hp = h + (size_t)g * NN * NC + so;
  const float* disg = dis + (size_t)g * NN;
  float dn = disg[node];
  float bv[4];
  #pragma unroll
  for (int i = 0; i < 4; ++i) {
    int p = so + i;
    bv[i] = b[(size_t)g * NC + (((p & 7) << 4) | (p >> 3))];
  }
  float a0[4], a1[4], a2[4], a3[4];
  half4 v = *(const half4*)(hp + (size_t)node * NC);   // self loop
  #pragma unroll
  for (int i = 0; i < 4; ++i) {
    a0[i] = GDIS ? dn * (float)v[i] : (float)v[i];
    a1[i] = 0.f; a2[i] = 0.f; a3[i] = 0.f;
  }
  int s = off[g * (NN + 1) + node];
  int e = s + deg[(size_t)g * NN + node];
  int j = s;
  for (; j + 4 <= e; j += 4) {
    int c0 = col[j], c1 = col[j + 1], c2 = col[j + 2], c3 = col[j + 3];
    half4 v0 = *(const half4*)(hp + (size_t)c0 * NC);
    half4 v1 = *(const half4*)(hp + (size_t)c1 * NC);
    half4 v2 = *(const half4*)(hp + (size_t)c2 * NC);
    half4 v3 = *(const half4*)(hp + (size_t)c3 * NC);
    if constexpr (GDIS) {
      float d0 = disg[c0], d1 = disg[c1], d2 = disg[c2], d3 = disg[c3];
      #pragma unroll
      for (int i = 0; i < 4; ++i) {
        MIXS(a0[i], v0[i], d0); MIXS(a1[i], v1[i], d1);
        MIXS(a2[i], v2[i], d2); MIXS(a3[i], v3[i], d3);
      }
    } else {
      #pragma unroll
      for (int i = 0; i < 4; ++i) {
        MIXACC(a0[i], v0[i]); MIXACC(a1[i], v1[i]);
        MIXACC(a2[i], v2[i]); MIXACC(a3[i], v3[i]);
      }
    }
  }
  for (; j < e; ++j) {
    int c = col[j];
    half4 vr = *(const half4*)(hp + (size_t)c * NC);
    if constexpr (GDIS) {
      float dd = disg[c];
      #pragma unroll
      for (int i = 0; i < 4; ++i) MIXS(a0[i], vr[i], dd);
    } else {
      #pragma unroll
      for (int i = 0; i < 4; ++i) MIXACC(a0[i], vr[i]);
    }
  }
  _Float16* og = outh + ((size_t)g * NN + node) * NC + so;   // slot layout
  half4 o;
  #pragma unroll
  for (int i = 0; i < 4; ++i)
    o[i] = (_Float16)((a0[i] + a1[i] + a2[i] + a3[i]) * dn + bv[i]);
  *(half4*)og = o;
}

// ----------------- Final aggregation (R12 exact): fp32 true-layout d_out.
__global__ __launch_bounds__(256) void agg_final_kernel(
    const _Float16* __restrict__ h, const int* __restrict__ off,
    const unsigned short* __restrict__ col, const unsigned short* __restrict__ deg,
    const float* __restrict__ dis, const float* __restrict__ b,
    float* __restrict__ outf) {
  int bid = blockIdx.x;
  int g = (bid & 7) >> 1;
  int sub = ((bid >> 3) << 1) | (bid & 1);
  int node = sub * 16 + (threadIdx.x >> 4);
  if (sub >= NN / 16) return;
  int l = threadIdx.x & 15;
  const half8* h8 = (const half8*)(h + (size_t)g * NN * NC);
  const float* disg = dis + (size_t)g * NN;
  float dn = disg[node];
  float a0[8], a1[8], a2[8], a3[8];
  half8 v = h8[(size_t)node * 16 + l];   // self loop
  #pragma unroll
  for (int i = 0; i < 8; ++i) {
    a0[i] = (float)v[i]; a1[i] = 0.f; a2[i] = 0.f; a3[i] = 0.f;
  }
  int s = off[g * (NN + 1) + node];
  int e = s + deg[(size_t)g * NN + node];
  int j = s;
  for (; j + 4 <= e; j += 4) {
    int c0 = col[j], c1 = col[j + 1], c2 = col[j + 2], c3 = col[j + 3];
    half8 v0 = h8[(size_t)c0 * 16 + l];
    half8 v1 = h8[(size_t)c1 * 16 + l];
    half8 v2 = h8[(size_t)c2 * 16 + l];
    half8 v3 = h8[(size_t)c3 * 16 + l];
    #pragma unroll
    for (int i = 0; i < 8; ++i) {
      MIXACC(a0[i], v0[i]); MIXACC(a1[i], v1[i]);
      MIXACC(a2[i], v2[i]); MIXACC(a3[i], v3[i]);
    }
  }
  for (; j < e; ++j) {
    half8 vr = h8[(size_t)col[j] * 16 + l];
    #pragma unroll
    for (int i = 0; i < 8; ++i) MIXACC(a0[i], vr[i]);
  }
  const float* bg = b + (size_t)g * NC;
  float* og = outf + ((size_t)g * NN + node) * NC;
  #pragma unroll
  for (int i = 0; i < 8; ++i) {   // slot l*8+i == true col i*16+l
    float val = (a0[i] + a1[i] + a2[i] + a3[i]) * dn + bg[i * 16 + l];
    og[i * 16 + l] = val;
  }
}

// ---------------------------------------------------------------- launcher
extern "C" void kernel_launch(void* const* d_in, const int* in_sizes, int n_in,
                              void* d_out, int out_size, void* d_ws, size_t ws_size,
                              hipStream_t stream) {
  const float* x  = (const float*)d_in[0];
  const int*   ei = (const int*)d_in[1];    // int64 narrowed to int32
  const float* W1 = (const float*)d_in[2];
  const float* b1 = (const float*)d_in[3];
  const float* W2 = (const float*)d_in[4];
  const float* b2 = (const float*)d_in[5];
  const float* W3 = (const float*)d_in[6];
  const float* b3 = (const float*)d_in[7];
  float* out = (float*)d_out;

  char* ws = (char*)d_ws;
  size_t p = 0;
  auto carve = [&](size_t bytes) -> char* {
    char* r = ws + p;
    p += (bytes + 255) & ~(size_t)255;
    return r;
  };
  int*            bktCur = (int*)           carve((size_t)NBT * 4);
  unsigned short* col    = (unsigned short*)carve((size_t)NBT * CAPQ * 2);  // 7.2MB
  int*            off    = (int*)           carve((size_t)NG * (NN + 1) * 4);
  unsigned short* deg    = (unsigned short*)carve((size_t)NG * NN * 2);
  float*          dis    = (float*)         carve((size_t)NG * NN * 4);
  _Float16*       hbuf   = (_Float16*)      carve((size_t)NG * NN * NC * 2); // 51.2MB
  // union region: rec (CSR build, dead after build_csr) | xh (inter-layer fp16)
  size_t ubytes = (size_t)NG * NN * NC * 2;                  // 51.2MB >= rec 14.5MB
  char*           uni    = carve(ubytes);
  unsigned int*   rec    = (unsigned int*)uni;
  _Float16*       xh     = (_Float16*)uni;

  init_cursors<<<(NBT + 255) / 256, 256, 0, stream>>>(bktCur);
  // layer-1 GEMM (independent of CSR) overlapped with edge scatter
  fat_gemm1_scatter<<<GEMM_BLKS + 784, 512, 0, stream>>>(x, W1, hbuf, ei, bktCur, rec);
  build_csr<<<dim3(NB, NG), 256, 0, stream>>>(rec, bktCur, col, off, deg, dis);

  dim3 ggrid((NN + 255) / 256, NG);
  int  agridS = (NN / 16) * 8;                 // slot-half split grid
  int  agridF = ((NN / 16 + 1) / 2) * 8;       // final agg (R12 mapping)

  // layer 1: hbuf(h'' unscaled, slot) -> xh(f16, slot)
  agg_slot_kernel<true><<<agridS, 256, 0, stream>>>(hbuf, off, col, deg, dis, b1, xh);
  // layer 2: xh(slot) -> hbuf(scaled, slot) -> xh(slot)
  gemm16_mfma_kernel<<<ggrid, 512, 0, stream>>>(xh, W2, dis, hbuf);
  agg_slot_kernel<false><<<agridS, 256, 0, stream>>>(hbuf, off, col, deg, dis, b2, xh);
  // layer 3: xh(slot) -> hbuf(scaled, slot) -> out(f32, true layout)
  gemm16_mfma_kernel<<<ggrid, 512, 0, stream>>>(xh, W3, dis, hbuf);
  agg_final_kernel<<<agridF, 256, 0, stream>>>(hbuf, off, col, deg, dis, b3, out);
}

// Round 15
// 443.090 us; speedup vs baseline: 1.0420x; 1.0420x over previous
//
#include <hip/hip_runtime.h>

#define NG 4
#define NN 50000
#define NE 800000
#define NC 128
#define NB 196              // ceil(NN/256) buckets of 256 nodes per graph
#define NBT (NG * NB)       // 784 total buckets
#define CAPB 48             // LDS bin capacity in scatter (lambda~21, +6 sigma)
#define LBS (NB + 1)        // lbin stride 197 (odd -> conflict-free flush)
#define CAPQ 4608           // fixed bucket capacity (lambda 4096, +8 sigma)
#define GEMM_BLKS 784       // 196 row-tiles (256 rows) x 4 graphs

typedef _Float16 half8 __attribute__((ext_vector_type(8)));
typedef _Float16 half4 __attribute__((ext_vector_type(4)));
typedef float f32x4 __attribute__((ext_vector_type(4)));

// ---------------------------------------------------------------- utilities
__global__ __launch_bounds__(256) void init_cursors(int* __restrict__ bktCur) {
  int i = blockIdx.x * blockDim.x + threadIdx.x;
  if (i < NBT) bktCur[i] = i * CAPQ;
}

// ---------------- FAT kernel: [gemm L1 (unscaled h'')]  ||  [bucket_scatter]
__global__ __launch_bounds__(512) void fat_gemm1_scatter(
    const float* __restrict__ x, const float* __restrict__ W,
    _Float16* __restrict__ h, const int* __restrict__ ei,
    int* __restrict__ bktCur, unsigned int* __restrict__ rec) {
  __shared__ char smem[65536];
  int bid = blockIdx.x;
  int tid = threadIdx.x;
  if (bid < GEMM_BLKS) {
    _Float16* Wt0 = (_Float16*)smem;
    _Float16* Wt1 = Wt0 + 128 * 128;
    int g = bid / 196;
    int row0 = (bid % 196) * 256;
    int lane = tid & 63;
    int wv = tid >> 6;          // 0..7
    int kc = lane >> 4;
    int lr = lane & 15;
    const float* Wg = W + (size_t)g * NC * NC;
    const float* xg = x + (size_t)g * NN * NC;
    {
      int n = tid & 127;
      int kq = (tid >> 7) & 3;
      #pragma unroll
      for (int it = 0; it < 8; ++it) {
        int k4 = it * 16 + kq * 4;
        float w0 = Wg[(size_t)(k4 + 0) * NC + n];
        float w1 = Wg[(size_t)(k4 + 1) * NC + n];
        float w2 = Wg[(size_t)(k4 + 2) * NC + n];
        float w3 = Wg[(size_t)(k4 + 3) * NC + n];
        half4 hi, lo;
        hi[0] = (_Float16)w0; lo[0] = (_Float16)(w0 - (float)hi[0]);
        hi[1] = (_Float16)w1; lo[1] = (_Float16)(w1 - (float)hi[1]);
        hi[2] = (_Float16)w2; lo[2] = (_Float16)(w2 - (float)hi[2]);
        hi[3] = (_Float16)w3; lo[3] = (_Float16)(w3 - (float)hi[3]);
        int chunk = k4 >> 3;
        int base = n * 128 + ((chunk ^ (n & 15)) << 3) + (k4 & 4);
        *(half4*)&Wt0[base] = hi;
        *(half4*)&Wt1[base] = lo;
      }
    }
    __syncthreads();
    f32x4 acc[2][8];
    #pragma unroll
    for (int mb = 0; mb < 2; ++mb)
      #pragma unroll
      for (int nb = 0; nb < 8; ++nb)
        acc[mb][nb] = (f32x4){0.f, 0.f, 0.f, 0.f};
    for (int kstep = 0; kstep < 4; ++kstep) {
      half8 ah[2], al[2];
      #pragma unroll
      for (int mb = 0; mb < 2; ++mb) {
        int row = row0 + wv * 32 + mb * 16 + lr;
        if (row > NN - 1) row = NN - 1;
        const float* xp = xg + (size_t)row * NC + kstep * 32 + kc * 8;
        float4 v0 = *(const float4*)xp;
        float4 v1 = *(const float4*)(xp + 4);
        float vv[8] = {v0.x, v0.y, v0.z, v0.w, v1.x, v1.y, v1.z, v1.w};
        #pragma unroll
        for (int i = 0; i < 8; ++i) {
          _Float16 t = (_Float16)vv[i];
          ah[mb][i] = t; al[mb][i] = (_Float16)(vv[i] - (float)t);
        }
      }
      #pragma unroll
      for (int nb = 0; nb < 8; ++nb) {
        int n = nb * 16 + lr;
        int chunk = kstep * 4 + kc;
        int boff = n * 128 + ((chunk ^ (n & 15)) << 3);
        half8 bh = *(const half8*)&Wt0[boff];
        half8 bl = *(const half8*)&Wt1[boff];
        #pragma unroll
        for (int mb = 0; mb < 2; ++mb) {
          acc[mb][nb] = __builtin_amdgcn_mfma_f32_16x16x32_f16(ah[mb], bh, acc[mb][nb], 0, 0, 0);
          acc[mb][nb] = __builtin_amdgcn_mfma_f32_16x16x32_f16(al[mb], bh, acc[mb][nb], 0, 0, 0);
          acc[mb][nb] = __builtin_amdgcn_mfma_f32_16x16x32_f16(ah[mb], bl, acc[mb][nb], 0, 0, 0);
        }
      }
    }
    _Float16* hg = h + (size_t)g * NN * NC;
    #pragma unroll
    for (int mb = 0; mb < 2; ++mb) {
      #pragma unroll
      for (int reg = 0; reg < 4; ++reg) {
        int row = row0 + wv * 32 + mb * 16 + kc * 4 + reg;
        if (row < NN) {
          half8 o;
          #pragma unroll
          for (int nb = 0; nb < 8; ++nb)
            o[nb] = (_Float16)acc[mb][nb][reg];     // UNSCALED h''
          *(half8*)(hg + (size_t)row * NC + lr * 8) = o;
        }
      }
    }
  } else {
    int* lcnt = (int*)smem;
    int* lbase = lcnt + NB;
    unsigned int* lbin = (unsigned int*)(smem + 2048);   // 37824B, fits
    int sb = bid - GEMM_BLKS;
    int g = sb / 196;
    int e0 = (sb % 196) * 4096;
    for (int i = tid; i < NB; i += 512) lcnt[i] = 0;
    __syncthreads();
    const int* srcp = ei + (size_t)g * 2 * NE;
    const int* dstp = srcp + NE;
    for (int t = tid; t < 4096; t += 512) {
      int e = e0 + t;
      if (e < NE) {
        int s = srcp[e], d = dstp[e];
        int b = d >> 8;
        unsigned int r = ((unsigned int)(d & 255) << 16) | (unsigned int)s;
        int pos = atomicAdd(&lcnt[b], 1);
        if (pos < CAPB) lbin[pos * LBS + b] = r;
        else { int gp = atomicAdd(&bktCur[g * NB + b], 1); rec[gp] = r; }  // rare
      }
    }
    __syncthreads();
    if (tid < NB) {
      int n = lcnt[tid]; if (n > CAPB) n = CAPB;
      lbase[tid] = n ? atomicAdd(&bktCur[g * NB + tid], n) : 0;
    }
    __syncthreads();
    int lane = tid & 63, wv = tid >> 6;
    for (int b = wv; b < NB; b += 8) {
      int n = lcnt[b]; if (n > CAPB) n = CAPB;
      if (lane < n) rec[lbase[b] + lane] = lbin[lane * LBS + b];
    }
  }
}

// Per (graph,bucket): LDS count -> scan -> rank into padded col[]. off/deg/dis.
__global__ __launch_bounds__(256) void build_csr(
    const unsigned int* __restrict__ rec, const int* __restrict__ bktCur,
    unsigned short* __restrict__ col, int* __restrict__ off,
    unsigned short* __restrict__ deg, float* __restrict__ dis) {
  __shared__ int cnt[256];
  __shared__ int offv[256];
  __shared__ int cnt2[256];
  __shared__ int wsum[4];
  int g = blockIdx.y, b = blockIdx.x;
  int idx = g * NB + b;
  int rb = idx * CAPQ, re = bktCur[idx];
  int tid = threadIdx.x;
  cnt[tid] = 0;
  __syncthreads();
  for (int j = rb + tid; j < re; j += 256)
    atomicAdd(&cnt[(rec[j] >> 16) & 255], 1);
  __syncthreads();
  int lane = tid & 63, wv = tid >> 6;
  int v = cnt[tid], incl = v;
  #pragma unroll
  for (int d2 = 1; d2 < 64; d2 <<= 1) {
    int t = __shfl_up(incl, d2, 64);
    if (lane >= d2) incl += t;
  }
  if (lane == 63) wsum[wv] = incl;
  __syncthreads();
  if (tid == 0) {
    int s = 0;
    #pragma unroll
    for (int w = 0; w < 4; ++w) { int t = wsum[w]; wsum[w] = s; s += t; }
  }
  __syncthreads();
  int excl = wsum[wv] + incl - v;
  offv[tid] = excl;
  cnt2[tid] = 0;
  int node = b * 256 + tid;
  if (node < NN) {
    off[g * (NN + 1) + node] = rb + excl;
    deg[(size_t)g * NN + node] = (unsigned short)v;
    dis[(size_t)g * NN + node] = rsqrtf((float)(v + 1));  // +1 self loop
  }
  __syncthreads();
  for (int j = rb + tid; j < re; j += 256) {
    unsigned int r = rec[j];
    int dl = (r >> 16) & 255;
    int p = rb + offv[dl] + atomicAdd(&cnt2[dl], 1);
    col[p] = (unsigned short)(r & 0xFFFF);
  }
}

// -------------------- fp16-input GEMM (layers 2,3): 512 thr, 256-row tile.
__global__ __launch_bounds__(512) void gemm16_mfma_kernel(
    const _Float16* __restrict__ x, const float* __restrict__ W,
    const float* __restrict__ dis, _Float16* __restrict__ h) {
  __shared__ _Float16 Wt[2][128 * 128];
  int g = blockIdx.y;
  int row0 = blockIdx.x * 256;
  int tid = threadIdx.x;
  int lane = tid & 63;
  int wv = tid >> 6;            // 0..7
  int kc = lane >> 4;
  int lr = lane & 15;
  const float* Wg = W + (size_t)g * NC * NC;
  const _Float16* xg = x + (size_t)g * NN * NC;
  {
    int n = tid & 127;
    int kq = (tid >> 7) & 3;
    #pragma unroll
    for (int it = 0; it < 8; ++it) {
      int k4 = it * 16 + kq * 4;
      float w0 = Wg[(size_t)(k4 + 0) * NC + n];
      float w1 = Wg[(size_t)(k4 + 1) * NC + n];
      float w2 = Wg[(size_t)(k4 + 2) * NC + n];
      float w3 = Wg[(size_t)(k4 + 3) * NC + n];
      half4 hi, lo;
      hi[0] = (_Float16)w0; lo[0] = (_Float16)(w0 - (float)hi[0]);
      hi[1] = (_Float16)w1; lo[1] = (_Float16)(w1 - (float)hi[1]);
      hi[2] = (_Float16)w2; lo[2] = (_Float16)(w2 - (float)hi[2]);
      hi[3] = (_Float16)w3; lo[3] = (_Float16)(w3 - (float)hi[3]);
      int chunk = k4 >> 3;
      int base = n * 128 + ((chunk ^ (n & 15)) << 3) + (k4 & 4);
      *(half4*)&Wt[0][base] = hi;
      *(half4*)&Wt[1][base] = lo;
    }
  }
  __syncthreads();
  f32x4 acc[2][8];
  #pragma unroll
  for (int mb = 0; mb < 2; ++mb)
    #pragma unroll
    for (int nb = 0; nb < 8; ++nb)
      acc[mb][nb] = (f32x4){0.f, 0.f, 0.f, 0.f};
  for (int kstep = 0; kstep < 4; ++kstep) {
    half8 ah[2];
    #pragma unroll
    for (int mb = 0; mb < 2; ++mb) {
      int row = row0 + wv * 32 + mb * 16 + lr;
      if (row > NN - 1) row = NN - 1;
      ah[mb] = *(const half8*)(xg + (size_t)row * NC + kstep * 32 + kc * 8);
    }
    #pragma unroll
    for (int nb = 0; nb < 8; ++nb) {
      int n = nb * 16 + lr;
      int chunk = kstep * 4 + kc;
      int boff = n * 128 + ((chunk ^ (n & 15)) << 3);
      half8 bh = *(const half8*)&Wt[0][boff];
      half8 bl = *(const half8*)&Wt[1][boff];
      #pragma unroll
      for (int mb = 0; mb < 2; ++mb) {
        acc[mb][nb] = __builtin_amdgcn_mfma_f32_16x16x32_f16(ah[mb], bh, acc[mb][nb], 0, 0, 0);
        acc[mb][nb] = __builtin_amdgcn_mfma_f32_16x16x32_f16(ah[mb], bl, acc[mb][nb], 0, 0, 0);
      }
    }
  }
  const float* disg = dis + (size_t)g * NN;
  _Float16* hg = h + (size_t)g * NN * NC;
  #pragma unroll
  for (int mb = 0; mb < 2; ++mb) {
    #pragma unroll
    for (int reg = 0; reg < 4; ++reg) {
      int row = row0 + wv * 32 + mb * 16 + kc * 4 + reg;
      if (row < NN) {
        float dsc = disg[row];
        half8 o;
        #pragma unroll
        for (int nb = 0; nb < 8; ++nb)
          o[nb] = (_Float16)(acc[mb][nb][reg] * dsc);
        *(half8*)(hg + (size_t)row * NC + lr * 8) = o;
      }
    }
  }
}

// --------------------------------------------- aggregation: gather over CSR
// GDIS=false (h' pre-scaled): out = dis[i]*(h'[i] + sum h'[s]) + b
// GDIS=true (h'' unscaled):  out = dis[i]*(dis[i]*h''[i] + sum dis[s]*h''[s]) + b
// 16 lanes/node, 4-deep chains, v_fma_mix accumulate.
#define MIXACC(A, H) A = fmaf((float)(H), 1.0f, A)
#define MIXS(A, H, S) A = fmaf((float)(H), S, A)
template <bool F16OUT, bool GDIS>
__global__ __launch_bounds__(256) void agg_kernel(
    const _Float16* __restrict__ h, const int* __restrict__ off,
    const unsigned short* __restrict__ col, const unsigned short* __restrict__ deg,
    const float* __restrict__ dis, const float* __restrict__ b,
    float* __restrict__ outf, _Float16* __restrict__ outh) {
  int bid = blockIdx.x;
  int g = (bid & 7) >> 1;                        // graph -> XCD pair
  int sub = ((bid >> 3) << 1) | (bid & 1);       // block index within graph
  int node = sub * 16 + (threadIdx.x >> 4);
  if (sub >= NN / 16) return;
  int l = threadIdx.x & 15;
  const half8* h8 = (const half8*)(h + (size_t)g * NN * NC);
  const float* disg = dis + (size_t)g * NN;
  float dn = disg[node];
  float a0[8], a1[8], a2[8], a3[8];
  half8 v = h8[(size_t)node * 16 + l];   // self loop
  #pragma unroll
  for (int i = 0; i < 8; ++i) {
    a0[i] = GDIS ? dn * (float)v[i] : (float)v[i];
    a1[i] = 0.f; a2[i] = 0.f; a3[i] = 0.f;
  }
  int s = off[g * (NN + 1) + node];
  int e = s + deg[(size_t)g * NN + node];
  int j = s;
  for (; j + 4 <= e; j += 4) {
    int c0 = col[j], c1 = col[j + 1], c2 = col[j + 2], c3 = col[j + 3];
    half8 v0 = h8[(size_t)c0 * 16 + l];
    half8 v1 = h8[(size_t)c1 * 16 + l];
    half8 v2 = h8[(size_t)c2 * 16 + l];
    half8 v3 = h8[(size_t)c3 * 16 + l];
    if constexpr (GDIS) {
      float d0 = disg[c0], d1 = disg[c1], d2 = disg[c2], d3 = disg[c3];
      #pragma unroll
      for (int i = 0; i < 8; ++i) {
        MIXS(a0[i], v0[i], d0); MIXS(a1[i], v1[i], d1);
        MIXS(a2[i], v2[i], d2); MIXS(a3[i], v3[i], d3);
      }
    } else {
      #pragma unroll
      for (int i = 0; i < 8; ++i) {
        MIXACC(a0[i], v0[i]); MIXACC(a1[i], v1[i]);
        MIXACC(a2[i], v2[i]); MIXACC(a3[i], v3[i]);
      }
    }
  }
  for (; j < e; ++j) {
    int c = col[j];
    half8 vr = h8[(size_t)c * 16 + l];
    if constexpr (GDIS) {
      float dd = disg[c];
      #pragma unroll
      for (int i = 0; i < 8; ++i) MIXS(a0[i], vr[i], dd);
    } else {
      #pragma unroll
      for (int i = 0; i < 8; ++i) MIXACC(a0[i], vr[i]);
    }
  }
  const float* bg = b + (size_t)g * NC;
  if constexpr (F16OUT) {
    _Float16* og = outh + ((size_t)g * NN + node) * NC;
    #pragma unroll
    for (int i = 0; i < 8; ++i) {   // true col c = i*16 + l
      float val = (a0[i] + a1[i] + a2[i] + a3[i]) * dn + bg[i * 16 + l];
      og[i * 16 + l] = (_Float16)val;
    }
  } else {
    float* og = outf + ((size_t)g * NN + node) * NC;
    #pragma unroll
    for (int i = 0; i < 8; ++i) {
      float val = (a0[i] + a1[i] + a2[i] + a3[i]) * dn + bg[i * 16 + l];
      og[i * 16 + l] = val;
    }
  }
}

// ---------------------------------------------------------------- launcher
extern "C" void kernel_launch(void* const* d_in, const int* in_sizes, int n_in,
                              void* d_out, int out_size, void* d_ws, size_t ws_size,
                              hipStream_t stream) {
  const float* x  = (const float*)d_in[0];
  const int*   ei = (const int*)d_in[1];    // int64 narrowed to int32
  const float* W1 = (const float*)d_in[2];
  const float* b1 = (const float*)d_in[3];
  const float* W2 = (const float*)d_in[4];
  const float* b2 = (const float*)d_in[5];
  const float* W3 = (const float*)d_in[6];
  const float* b3 = (const float*)d_in[7];
  float* out = (float*)d_out;

  char* ws = (char*)d_ws;
  size_t p = 0;
  auto carve = [&](size_t bytes) -> char* {
    char* r = ws + p;
    p += (bytes + 255) & ~(size_t)255;
    return r;
  };
  int*            bktCur = (int*)           carve((size_t)NBT * 4);
  unsigned short* col    = (unsigned short*)carve((size_t)NBT * CAPQ * 2);  // 7.2MB
  int*            off    = (int*)           carve((size_t)NG * (NN + 1) * 4);
  unsigned short* deg    = (unsigned short*)carve((size_t)NG * NN * 2);
  float*          dis    = (float*)         carve((size_t)NG * NN * 4);
  _Float16*       hbuf   = (_Float16*)      carve((size_t)NG * NN * NC * 2); // 51.2MB
  // union region: rec (CSR build, dead after build_csr) | xh (inter-layer fp16)
  size_t ubytes = (size_t)NG * NN * NC * 2;                  // 51.2MB >= rec 14.5MB
  char*           uni    = carve(ubytes);
  unsigned int*   rec    = (unsigned int*)uni;
  _Float16*       xh     = (_Float16*)uni;

  init_cursors<<<(NBT + 255) / 256, 256, 0, stream>>>(bktCur);
  // layer-1 GEMM (independent of CSR) overlapped with edge scatter
  fat_gemm1_scatter<<<GEMM_BLKS + 784, 512, 0, stream>>>(x, W1, hbuf, ei, bktCur, rec);
  build_csr<<<dim3(NB, NG), 256, 0, stream>>>(rec, bktCur, col, off, deg, dis);

  dim3 ggrid((NN + 255) / 256, NG);
  int  agrid = ((NN / 16 + 1) / 2) * 8;   // 1563 * 8 = 12504 (XCD-affine)

  // layer 1: hbuf(h'' unscaled) -> xh(f16)  [agg applies dis at gather]
  agg_kernel<true, true><<<agrid, 256, 0, stream>>>(hbuf, off, col, deg, dis, b1, nullptr, xh);
  // layer 2: xh -> hbuf(scaled) -> xh
  gemm16_mfma_kernel<<<ggrid, 512, 0, stream>>>(xh, W2, dis, hbuf);
  agg_kernel<true, false><<<agrid, 256, 0, stream>>>(hbuf, off, col, deg, dis, b2, nullptr, xh);
  // layer 3: xh -> hbuf(scaled) -> out(f32)
  gemm16_mfma_kernel<<<ggrid, 512, 0, stream>>>(xh, W3, dis, hbuf);
  agg_kernel<false, false><<<agrid, 256, 0, stream>>>(hbuf, off, col, deg, dis, b3, out, nullptr);
}